// Round 2
// baseline (211.792 us; speedup 1.0000x reference)
//
#include <hip/hip_runtime.h>

typedef unsigned short u16;
typedef unsigned int u32;
typedef __bf16 bf16x8 __attribute__((ext_vector_type(8)));
typedef __bf16 bf16x2 __attribute__((ext_vector_type(2)));
typedef float f32x4 __attribute__((ext_vector_type(4)));

#define QSCALE 0.18033688011112f  // 0.125 * log2(e): folded into Q so p = 2^s

__device__ __forceinline__ u16 f2bf(float f) {
  u32 u = __builtin_bit_cast(u32, f);
  u += 0x7fffu + ((u >> 16) & 1u);   // RNE
  return (u16)(u >> 16);
}

// packed f32x2 -> bf16x2 (RNE), emits v_cvt_pk_bf16_f32 on gfx950
__device__ __forceinline__ u32 pkbf(float a, float b) {
  bf16x2 t = {(__bf16)a, (__bf16)b};
  return __builtin_bit_cast(u32, t);
}

__device__ __forceinline__ bf16x8 as_bf16x8(uint4 v) {
  return __builtin_bit_cast(bf16x8, v);
}

// async global->LDS, 16B per lane; LDS dest = wave-uniform base + lane*16
__device__ __forceinline__ void async16(const void* g, void* l) {
  __builtin_amdgcn_global_load_lds(
      (__attribute__((address_space(1))) void*)(g),
      (__attribute__((address_space(3))) void*)(l), 16, 0, 0);
}

// ---------------- merged prep: cast xq/xkv to bf16 + transpose-cast 3 weights
__global__ void prep_kernel(const float* __restrict__ xq, const float* __restrict__ xkv,
                            const float* __restrict__ Wq, const float* __restrict__ Wkv,
                            const float* __restrict__ Wo,
                            u16* __restrict__ Xq16, u16* __restrict__ Xkv16,
                            u16* __restrict__ WqT, u16* __restrict__ WkvT,
                            u16* __restrict__ WoT) {
  const int bid = blockIdx.x, tid = threadIdx.x;
  if (bid < 8192) {
    int i = bid * 256 + tid;
    const float* s; u16* d; int j;
    if (i < 1048576) { s = xq; d = Xq16; j = i; }
    else             { s = xkv; d = Xkv16; j = i - 1048576; }
    float4 v = ((const float4*)s)[j];
    ushort4 o;
    o.x = f2bf(v.x); o.y = f2bf(v.y); o.z = f2bf(v.z); o.w = f2bf(v.w);
    ((ushort4*)d)[j] = o;
    return;
  }
  const int b2 = bid - 8192;
  const int z = b2 >> 11, rem = b2 & 2047;
  const int by = rem >> 6, bx = rem & 63;
  const float* src; u16* dst; int Nd;
  if (z == 0)      { src = Wq;  dst = WqT;  Nd = 1024; }
  else if (z == 1) { src = Wkv; dst = WkvT; Nd = 2048; }
  else             { src = Wo;  dst = WoT;  Nd = 1024; }
  const int n0 = bx * 32, k0 = by * 32;
  if (n0 >= Nd) return;
  __shared__ float tile[32][33];
  const int tx = tid & 31, ty = tid >> 5;  // 32 x 8
#pragma unroll
  for (int j = 0; j < 4; ++j)
    tile[ty + 8 * j][tx] = src[(size_t)(k0 + ty + 8 * j) * Nd + n0 + tx];
  __syncthreads();
#pragma unroll
  for (int j = 0; j < 4; ++j)
    dst[(size_t)(n0 + ty + 8 * j) * 1024 + k0 + tx] = f2bf(tile[tx][ty + 8 * j]);
}

// ---------------------------------------------------------------- GEMM core
template <int MI>
static __device__ __forceinline__ void gemm_core(
    const u16* __restrict__ A, const u16* __restrict__ Bt, int m0,
    uint4* sA, uint4* sB, f32x4 (*acc)[4]) {
  const int tid = threadIdx.x;
  const int wv = tid >> 6, lane = tid & 63;
  const int quad = lane >> 4, l16 = lane & 15;
  const int wm = (wv >> 1) * (MI * 16), wn = (wv & 1) * 64;

  const int ib0 = wv * 128 + lane, ib1 = ib0 + 64;      // B: 512 slots
  const int br0 = ib0 >> 2, bc0 = (ib0 & 3) ^ ((br0 >> 1) & 3);
  const int br1 = ib1 >> 2, bc1 = (ib1 & 3) ^ ((br1 >> 1) & 3);
  const u16* gB0 = Bt + (size_t)br0 * 1024 + bc0 * 8;
  const u16* gB1 = Bt + (size_t)br1 * 1024 + bc1 * 8;

  const int ia0 = wv * (MI * 32) + lane;                // A: MI*128 slots
  const int ar0 = ia0 >> 2, ac0 = (ia0 & 3) ^ ((ar0 >> 1) & 3);
  const u16* gA0 = A + (size_t)(m0 + ar0) * 1024 + ac0 * 8;
  const int ia1 = ia0 + 64;
  const int ar1 = ia1 >> 2, ac1 = (ia1 & 3) ^ ((ar1 >> 1) & 3);
  const u16* gA1 = A + (size_t)(m0 + ar1) * 1024 + ac1 * 8;
  uint4* sAw = sA + wv * (MI * 32);
  uint4* sBw = sB + wv * 128;

  for (int k0 = 0; k0 < 1024; k0 += 32) {
    __syncthreads();
    async16(gA0 + k0, sAw);
    if (MI == 4) async16(gA1 + k0, sAw + 64);
    async16(gB0 + k0, sBw);
    async16(gB1 + k0, sBw + 64);
    __syncthreads();

    bf16x8 af[MI], bfr[4];
#pragma unroll
    for (int mi = 0; mi < MI; ++mi) {
      int r = wm + mi * 16 + l16;
      af[mi] = as_bf16x8(sA[r * 4 + (quad ^ ((r >> 1) & 3))]);
    }
#pragma unroll
    for (int ni = 0; ni < 4; ++ni) {
      int r = wn + ni * 16 + l16;
      bfr[ni] = as_bf16x8(sB[r * 4 + (quad ^ ((r >> 1) & 3))]);
    }
#pragma unroll
    for (int mi = 0; mi < MI; ++mi)
#pragma unroll
      for (int ni = 0; ni < 4; ++ni)
        acc[mi][ni] = __builtin_amdgcn_mfma_f32_16x16x32_bf16(
            af[mi], bfr[ni], acc[mi][ni], 0, 0, 0);
  }
}

// ------------------------------------- fused Q/K/V projection GEMM (N = 3072 virtual)
// Q, K -> plain [4096][1024] bf16 (coalesced); V -> [bh][dh][skv] packed ushort4.
__global__ __launch_bounds__(256, 3) void gemm_qkv(
    const u16* __restrict__ Xq, const u16* __restrict__ Xkv,
    const u16* __restrict__ WqT, const u16* __restrict__ WkvT,
    const float* __restrict__ bq, const float* __restrict__ bkv,
    u16* __restrict__ Qd, u16* __restrict__ Kd, u16* __restrict__ Vd) {
  __shared__ uint4 sA[512], sB[512];
  f32x4 acc[4][4] = {};
  const int n0 = blockIdx.x * 128, m0 = blockIdx.y * 128;
  const u16* A = (n0 < 1024) ? Xq : Xkv;
  const u16* Bt = (n0 < 1024) ? (WqT + (size_t)n0 * 1024)
                              : (WkvT + (size_t)(n0 - 1024) * 1024);
  const float* bias = (n0 < 1024) ? (bq + n0) : (bkv + (n0 - 1024));
  gemm_core<4>(A, Bt, m0, sA, sB, acc);

  const int tid = threadIdx.x, wv = tid >> 6, lane = tid & 63;
  const int quad = lane >> 4, l16 = lane & 15;
  const int wm = (wv >> 1) * 64, wn = (wv & 1) * 64;
  const int bb = m0 >> 11;
  const int gmb = m0 + wm + quad * 4;            // global row base (b*2048+ss)
  const int ssb = (m0 & 2047) + wm + quad * 4;   // seq base
#pragma unroll
  for (int ni = 0; ni < 4; ++ni) {
    const int gn = n0 + wn + ni * 16 + l16;      // virtual col; region uniform per ni
    const float bvn = bias[wn + ni * 16 + l16];
    if (gn < 1024) {                             // Q plain, pre-scaled
      u16* base = Qd + gn;
#pragma unroll
      for (int mi = 0; mi < 4; ++mi)
#pragma unroll
        for (int r = 0; r < 4; ++r)
          base[(size_t)(gmb + mi * 16 + r) * 1024] = f2bf((acc[mi][ni][r] + bvn) * QSCALE);
    } else if (gn < 2048) {                      // K plain
      u16* base = Kd + (gn - 1024);
#pragma unroll
      for (int mi = 0; mi < 4; ++mi)
#pragma unroll
        for (int r = 0; r < 4; ++r)
          base[(size_t)(gmb + mi * 16 + r) * 1024] = f2bf(acc[mi][ni][r] + bvn);
    } else {                                     // V^T: [bh][dh][skv], packed x4
      const int col = gn - 2048, hh = col >> 6, dh = col & 63;
      u16* base = Vd + ((size_t)(bb * 16 + hh) * 64 + dh) * 2048 + ssb;
#pragma unroll
      for (int mi = 0; mi < 4; ++mi) {
        ushort4 o;
        o.x = f2bf(acc[mi][ni][0] + bvn);
        o.y = f2bf(acc[mi][ni][1] + bvn);
        o.z = f2bf(acc[mi][ni][2] + bvn);
        o.w = f2bf(acc[mi][ni][3] + bvn);
        *(ushort4*)(base + mi * 16) = o;
      }
    }
  }
}

// ---------------------------------------------------------------- flash attention
// R5: producer/consumer wave specialization. 512 threads = 8 waves, BQ=128.
// Waves 0-3 (producers): stage K, read K frags, QK^T, exp2, write P -> sP[t&1].
// Waves 4-7 (consumers): stage V(t), read P(t-1) + V(t-1), PV + lsum, epilogue.
// Rationale (R4 post-mortem): occupancy was GRID-limited at 2 waves/SIMD (512
// blocks x 4 waves), leaving ~50% of cycles with no issuable wave; the serial
// QK->exp->PV chain per wave cannot be hidden. Splitting roles doubles waves/CU
// to 16 (4/SIMD) at the SAME grid: each SIMD hosts producer+consumer waves whose
// trans (exp2) and matrix (PV) work overlap structurally. All hand-offs
// (P bank, V buffer, K buffer) cross exactly one __syncthreads; sP double-bank
// is now load-bearing (producer writes bank t&1 while consumer reads bank
// (t-1)&1). V staged at iter t, consumed at t+1 -> no register carry needed.
// LDS unchanged 69632 B -> still 2 blocks/CU. XCD-aware flat grid unchanged.
__global__ __launch_bounds__(512, 4) void flash_attn(
    const u16* __restrict__ Q, const u16* __restrict__ K,
    const u16* __restrict__ V, u16* __restrict__ O) {
  __shared__ uint4 sK[2][512];              // 64 kv x 64 dh, x2 buffers
  __shared__ uint4 sV[2][512];              // 64 dh x 64 kv (V^T), x2
  __shared__ __align__(16) u16 sP[2][4][32][72];   // double-banked P (cross-wave)

  const int tid = threadIdx.x;
  const int wv = tid >> 6, lane = tid & 63;
  const int wg = wv & 3;                    // wave-group index within role
  const bool prod = wv < 4;
  const int quad = lane >> 4, l16 = lane & 15;
  const int hb = blockIdx.x & 31;           // fast dim: (h, b) -> fixes XCD
  const int q0 = (blockIdx.x >> 5) * 128;   // slow dim: q-block
  const int h = hb & 15, bz = hb >> 4;

  // Q,K plain [B*S][1024]; V^T [bh][dh][skv]
  const u16* Qb = Q + ((size_t)(bz * 2048 + q0)) * 1024 + h * 64;
  const u16* Kb = K + ((size_t)(bz * 2048)) * 1024 + h * 64;
  const u16* Vb = V + ((size_t)(bz * 16 + h)) * 64 * 2048;

  const int i0 = wg * 128 + lane, i1 = i0 + 64;
  const int kr0 = i0 >> 3, kr1 = i1 >> 3;
  const int wo = wg * 128;

  // ---- producer state
  bf16x8 qf[2][2];
  const u16 *gK0 = nullptr, *gK1 = nullptr;
  // ---- consumer state
  f32x4 oacc[2][4] = {};
  f32x4 lsum[2] = {};
  const uint4 ones4 = {0x3F803F80u, 0x3F803F80u, 0x3F803F80u, 0x3F803F80u};
  const bf16x8 ones = as_bf16x8(ones4);
  const u16 *gV0 = nullptr, *gV1 = nullptr;

  if (prod) {
    const int kck0 = (i0 & 7) ^ ((i0 >> 5) & 7);   // K swizzle: ^((row>>2)&7)
    const int kck1 = (i1 & 7) ^ ((i1 >> 5) & 7);
    gK0 = Kb + (size_t)kr0 * 1024 + kck0 * 8;
    gK1 = Kb + (size_t)kr1 * 1024 + kck1 * 8;
    // Q frags resident (A-layout: m=l16, k=quad*8+j)
#pragma unroll
    for (int rb = 0; rb < 2; ++rb) {
      const uint4* qp = (const uint4*)(Qb + (size_t)(wg * 32 + rb * 16 + l16) * 1024);
      qf[rb][0] = as_bf16x8(qp[quad]);
      qf[rb][1] = as_bf16x8(qp[4 + quad]);
    }
    // prologue: K tile 0 -> buffer 0
    async16(gK0, &sK[0][wo]);
    async16(gK1, &sK[0][wo + 64]);
  } else {
    const int vck0 = (i0 & 7) ^ (kr0 & 7);         // V swizzle: ^(row&7)
    const int vck1 = (i1 & 7) ^ (kr1 & 7);
    gV0 = Vb + (size_t)kr0 * 2048 + vck0 * 8;
    gV1 = Vb + (size_t)kr1 * 2048 + vck1 * 8;
  }

#pragma unroll 2
  for (int t = 0; t < 32; ++t) {
    const int cur = t & 1;
    __syncthreads();   // drains staging; publishes P(t-1), V(t-1)

    if (prod) {
      if (t < 31) {
        const size_t ko = (size_t)(t + 1) * 64 * 1024;   // 64 K rows
        async16(gK0 + ko, &sK[cur ^ 1][wo]);
        async16(gK1 + ko, &sK[cur ^ 1][wo + 64]);
      }
      const uint4* K_ = sK[cur];
      bf16x8 bK0[4], bK1[4];
#pragma unroll
      for (int ni = 0; ni < 4; ++ni) {
        int rr = l16 * 4 + ni;                     // kv = 4*l16+ni
        bK0[ni] = as_bf16x8(K_[rr * 8 + (quad ^ (l16 & 7))]);
        bK1[ni] = as_bf16x8(K_[rr * 8 + ((4 + quad) ^ (l16 & 7))]);
      }
#pragma unroll
      for (int rb = 0; rb < 2; ++rb) {
        f32x4 s4[4];
#pragma unroll
        for (int ni = 0; ni < 4; ++ni) {
          f32x4 a = {0.f, 0.f, 0.f, 0.f};
          a = __builtin_amdgcn_mfma_f32_16x16x32_bf16(qf[rb][0], bK0[ni], a, 0, 0, 0);
          a = __builtin_amdgcn_mfma_f32_16x16x32_bf16(qf[rb][1], bK1[ni], a, 0, 0, 0);
          s4[ni] = a;
        }
#pragma unroll
        for (int r = 0; r < 4; ++r) {              // p = 2^s; v_cvt_pk + b64 write
          uint2 pk;
          pk.x = pkbf(exp2f(s4[0][r]), exp2f(s4[1][r]));
          pk.y = pkbf(exp2f(s4[2][r]), exp2f(s4[3][r]));
          *(uint2*)&sP[cur][wg][rb * 16 + quad * 4 + r][l16 * 4] = pk;
        }
      }
    } else {
      // stage V(t) -> sV[cur] (consumed next iter)
      const int vo = t * 64;                       // 64 kv cols
      async16(gV0 + vo, &sV[cur][wo]);
      async16(gV1 + vo, &sV[cur][wo + 64]);
      if (t) {
        const uint4* V_ = sV[cur ^ 1];
        bf16x8 vf0[4], vf1[4];
#pragma unroll
        for (int ni = 0; ni < 4; ++ni) {
          int vvv = ni * 16 + l16;
          vf0[ni] = as_bf16x8(V_[vvv * 8 + (quad ^ (vvv & 7))]);
          vf1[ni] = as_bf16x8(V_[vvv * 8 + ((4 + quad) ^ (vvv & 7))]);
        }
        __builtin_amdgcn_s_setprio(1);
#pragma unroll
        for (int rb = 0; rb < 2; ++rb) {
          bf16x8 pf0 = as_bf16x8(*(const uint4*)&sP[cur ^ 1][wg][rb * 16 + l16][quad * 8]);
          bf16x8 pf1 = as_bf16x8(*(const uint4*)&sP[cur ^ 1][wg][rb * 16 + l16][32 + quad * 8]);
          lsum[rb] = __builtin_amdgcn_mfma_f32_16x16x32_bf16(pf0, ones, lsum[rb], 0, 0, 0);
          lsum[rb] = __builtin_amdgcn_mfma_f32_16x16x32_bf16(pf1, ones, lsum[rb], 0, 0, 0);
#pragma unroll
          for (int ni = 0; ni < 4; ++ni) {
            oacc[rb][ni] = __builtin_amdgcn_mfma_f32_16x16x32_bf16(pf0, vf0[ni], oacc[rb][ni], 0, 0, 0);
            oacc[rb][ni] = __builtin_amdgcn_mfma_f32_16x16x32_bf16(pf1, vf1[ni], oacc[rb][ni], 0, 0, 0);
          }
        }
        __builtin_amdgcn_s_setprio(0);
      }
    }
  }

  // drain: PV for tile 31 (P in bank 1, V(31) staged into sV[1])
  __syncthreads();
  if (!prod) {
    const uint4* V_ = sV[1];
    bf16x8 vf0[4], vf1[4];
#pragma unroll
    for (int ni = 0; ni < 4; ++ni) {
      int vvv = ni * 16 + l16;
      vf0[ni] = as_bf16x8(V_[vvv * 8 + (quad ^ (vvv & 7))]);
      vf1[ni] = as_bf16x8(V_[vvv * 8 + ((4 + quad) ^ (vvv & 7))]);
    }
    __builtin_amdgcn_s_setprio(1);
#pragma unroll
    for (int rb = 0; rb < 2; ++rb) {
      bf16x8 pf0 = as_bf16x8(*(const uint4*)&sP[1][wg][rb * 16 + l16][quad * 8]);
      bf16x8 pf1 = as_bf16x8(*(const uint4*)&sP[1][wg][rb * 16 + l16][32 + quad * 8]);
      lsum[rb] = __builtin_amdgcn_mfma_f32_16x16x32_bf16(pf0, ones, lsum[rb], 0, 0, 0);
      lsum[rb] = __builtin_amdgcn_mfma_f32_16x16x32_bf16(pf1, ones, lsum[rb], 0, 0, 0);
#pragma unroll
      for (int ni = 0; ni < 4; ++ni) {
        oacc[rb][ni] = __builtin_amdgcn_mfma_f32_16x16x32_bf16(pf0, vf0[ni], oacc[rb][ni], 0, 0, 0);
        oacc[rb][ni] = __builtin_amdgcn_mfma_f32_16x16x32_bf16(pf1, vf1[ni], oacc[rb][ni], 0, 0, 0);
      }
    }
    __builtin_amdgcn_s_setprio(0);

    // epilogue: O16 plain [4096][1024] bf16, normalized by MFMA row-sums
#pragma unroll
    for (int rb = 0; rb < 2; ++rb) {
      u16* Ob = O + ((size_t)(bz * 2048 + q0 + wg * 32 + rb * 16 + quad * 4)) * 1024
                  + h * 64;
#pragma unroll
      for (int r = 0; r < 4; ++r) {
        float rl = 1.0f / lsum[rb][r];
#pragma unroll
        for (int ni = 0; ni < 4; ++ni)
          Ob[(size_t)r * 1024 + ni * 16 + l16] = f2bf(oacc[rb][ni][r] * rl);
      }
    }
  }
}

// ---------------------------------------------------------------- output projection
__global__ __launch_bounds__(256, 2) void gemm_out(
    const u16* __restrict__ A, const u16* __restrict__ Bt,
    const float* __restrict__ bias, float* __restrict__ C) {
  __shared__ uint4 sA[256], sB[512];
  f32x4 acc[2][4] = {};
  const int n0 = blockIdx.x * 128, m0 = blockIdx.y * 64;
  gemm_core<2>(A, Bt + (size_t)n0 * 1024, m0, sA, sB, acc);

  const int tid = threadIdx.x, wv = tid >> 6, lane = tid & 63;
  const int quad = lane >> 4, l16 = lane & 15;
  const int wm = (wv >> 1) * 32, wn = (wv & 1) * 64;
  float bv[4];
#pragma unroll
  for (int ni = 0; ni < 4; ++ni) bv[ni] = bias[n0 + wn + ni * 16 + l16];
#pragma unroll
  for (int mi = 0; mi < 2; ++mi)
#pragma unroll
    for (int ni = 0; ni < 4; ++ni)
#pragma unroll
      for (int r = 0; r < 4; ++r) {
        int gm = m0 + wm + mi * 16 + quad * 4 + r;
        int gn = n0 + wn + ni * 16 + l16;
        C[(size_t)gm * 1024 + gn] = acc[mi][ni][r] + bv[ni];
      }
}

extern "C" void kernel_launch(void* const* d_in, const int* in_sizes, int n_in,
                              void* d_out, int out_size, void* d_ws, size_t ws_size,
                              hipStream_t stream) {
  const float* xq  = (const float*)d_in[0];
  const float* xkv = (const float*)d_in[1];
  const float* Wq  = (const float*)d_in[2];
  const float* bq  = (const float*)d_in[3];
  const float* Wkv = (const float*)d_in[4];
  const float* bkv = (const float*)d_in[5];
  const float* Wo  = (const float*)d_in[6];
  const float* bo  = (const float*)d_in[7];
  float* out = (float*)d_out;

  char* p = (char*)d_ws;                       // 56 MiB total
  u16* Xq16  = (u16*)p; p += (size_t)8 << 20;  // [4096][1024] bf16
  u16* Xkv16 = (u16*)p; p += (size_t)8 << 20;
  u16* WqT   = (u16*)p; p += (size_t)2 << 20;  // [1024][1024]
  u16* WkvT  = (u16*)p; p += (size_t)4 << 20;  // [2048][1024]
  u16* WoT   = (u16*)p; p += (size_t)2 << 20;
  u16* Q16   = (u16*)p; p += (size_t)8 << 20;  // plain [4096][1024], pre-scaled
  u16* K16   = (u16*)p; p += (size_t)8 << 20;  // plain [4096][1024]
  u16* Vt16  = (u16*)p; p += (size_t)8 << 20;  // [bh][dh][skv]
  u16* O16   = (u16*)p; p += (size_t)8 << 20;  // plain [4096][1024]

  prep_kernel<<<14336, 256, 0, stream>>>(xq, xkv, Wq, Wkv, Wo,
                                         Xq16, Xkv16, WqT, WkvT, WoT);
  gemm_qkv<<<dim3(24, 32), 256, 0, stream>>>(Xq16, Xkv16, WqT, WkvT, bq, bkv,
                                             Q16, K16, Vt16);
  flash_attn<<<512, 512, 0, stream>>>(Q16, K16, Vt16, O16);
  gemm_out<<<dim3(8, 64), 256, 0, stream>>>(O16, WoT, bo, out);
}

// Round 3
// 210.744 us; speedup vs baseline: 1.0050x; 1.0050x over previous
//
#include <hip/hip_runtime.h>

typedef unsigned short u16;
typedef unsigned int u32;
typedef __bf16 bf16x8 __attribute__((ext_vector_type(8)));
typedef __bf16 bf16x2 __attribute__((ext_vector_type(2)));
typedef float f32x4 __attribute__((ext_vector_type(4)));
typedef float f32x16 __attribute__((ext_vector_type(16)));

#define QSCALE 0.18033688011112f  // 0.125 * log2(e): folded into Q so p = 2^s

__device__ __forceinline__ u16 f2bf(float f) {
  u32 u = __builtin_bit_cast(u32, f);
  u += 0x7fffu + ((u >> 16) & 1u);   // RNE
  return (u16)(u >> 16);
}

// packed f32x2 -> bf16x2 (RNE), emits v_cvt_pk_bf16_f32 on gfx950
__device__ __forceinline__ u32 pkbf(float a, float b) {
  bf16x2 t = {(__bf16)a, (__bf16)b};
  return __builtin_bit_cast(u32, t);
}

__device__ __forceinline__ bf16x8 as_bf16x8(uint4 v) {
  return __builtin_bit_cast(bf16x8, v);
}

// async global->LDS, 16B per lane; LDS dest = wave-uniform base + lane*16
__device__ __forceinline__ void async16(const void* g, void* l) {
  __builtin_amdgcn_global_load_lds(
      (__attribute__((address_space(1))) void*)(g),
      (__attribute__((address_space(3))) void*)(l), 16, 0, 0);
}

// ---------------- merged prep: cast xq/xkv to bf16 + transpose-cast 3 weights
__global__ void prep_kernel(const float* __restrict__ xq, const float* __restrict__ xkv,
                            const float* __restrict__ Wq, const float* __restrict__ Wkv,
                            const float* __restrict__ Wo,
                            u16* __restrict__ Xq16, u16* __restrict__ Xkv16,
                            u16* __restrict__ WqT, u16* __restrict__ WkvT,
                            u16* __restrict__ WoT) {
  const int bid = blockIdx.x, tid = threadIdx.x;
  if (bid < 8192) {
    int i = bid * 256 + tid;
    const float* s; u16* d; int j;
    if (i < 1048576) { s = xq; d = Xq16; j = i; }
    else             { s = xkv; d = Xkv16; j = i - 1048576; }
    float4 v = ((const float4*)s)[j];
    ushort4 o;
    o.x = f2bf(v.x); o.y = f2bf(v.y); o.z = f2bf(v.z); o.w = f2bf(v.w);
    ((ushort4*)d)[j] = o;
    return;
  }
  const int b2 = bid - 8192;
  const int z = b2 >> 11, rem = b2 & 2047;
  const int by = rem >> 6, bx = rem & 63;
  const float* src; u16* dst; int Nd;
  if (z == 0)      { src = Wq;  dst = WqT;  Nd = 1024; }
  else if (z == 1) { src = Wkv; dst = WkvT; Nd = 2048; }
  else             { src = Wo;  dst = WoT;  Nd = 1024; }
  const int n0 = bx * 32, k0 = by * 32;
  if (n0 >= Nd) return;
  __shared__ float tile[32][33];
  const int tx = tid & 31, ty = tid >> 5;  // 32 x 8
#pragma unroll
  for (int j = 0; j < 4; ++j)
    tile[ty + 8 * j][tx] = src[(size_t)(k0 + ty + 8 * j) * Nd + n0 + tx];
  __syncthreads();
#pragma unroll
  for (int j = 0; j < 4; ++j)
    dst[(size_t)(n0 + ty + 8 * j) * 1024 + k0 + tx] = f2bf(tile[tx][ty + 8 * j]);
}

// ---------------------------------------------------------------- GEMM core
template <int MI>
static __device__ __forceinline__ void gemm_core(
    const u16* __restrict__ A, const u16* __restrict__ Bt, int m0,
    uint4* sA, uint4* sB, f32x4 (*acc)[4]) {
  const int tid = threadIdx.x;
  const int wv = tid >> 6, lane = tid & 63;
  const int quad = lane >> 4, l16 = lane & 15;
  const int wm = (wv >> 1) * (MI * 16), wn = (wv & 1) * 64;

  const int ib0 = wv * 128 + lane, ib1 = ib0 + 64;      // B: 512 slots
  const int br0 = ib0 >> 2, bc0 = (ib0 & 3) ^ ((br0 >> 1) & 3);
  const int br1 = ib1 >> 2, bc1 = (ib1 & 3) ^ ((br1 >> 1) & 3);
  const u16* gB0 = Bt + (size_t)br0 * 1024 + bc0 * 8;
  const u16* gB1 = Bt + (size_t)br1 * 1024 + bc1 * 8;

  const int ia0 = wv * (MI * 32) + lane;                // A: MI*128 slots
  const int ar0 = ia0 >> 2, ac0 = (ia0 & 3) ^ ((ar0 >> 1) & 3);
  const u16* gA0 = A + (size_t)(m0 + ar0) * 1024 + ac0 * 8;
  const int ia1 = ia0 + 64;
  const int ar1 = ia1 >> 2, ac1 = (ia1 & 3) ^ ((ar1 >> 1) & 3);
  const u16* gA1 = A + (size_t)(m0 + ar1) * 1024 + ac1 * 8;
  uint4* sAw = sA + wv * (MI * 32);
  uint4* sBw = sB + wv * 128;

  for (int k0 = 0; k0 < 1024; k0 += 32) {
    __syncthreads();
    async16(gA0 + k0, sAw);
    if (MI == 4) async16(gA1 + k0, sAw + 64);
    async16(gB0 + k0, sBw);
    async16(gB1 + k0, sBw + 64);
    __syncthreads();

    bf16x8 af[MI], bfr[4];
#pragma unroll
    for (int mi = 0; mi < MI; ++mi) {
      int r = wm + mi * 16 + l16;
      af[mi] = as_bf16x8(sA[r * 4 + (quad ^ ((r >> 1) & 3))]);
    }
#pragma unroll
    for (int ni = 0; ni < 4; ++ni) {
      int r = wn + ni * 16 + l16;
      bfr[ni] = as_bf16x8(sB[r * 4 + (quad ^ ((r >> 1) & 3))]);
    }
#pragma unroll
    for (int mi = 0; mi < MI; ++mi)
#pragma unroll
      for (int ni = 0; ni < 4; ++ni)
        acc[mi][ni] = __builtin_amdgcn_mfma_f32_16x16x32_bf16(
            af[mi], bfr[ni], acc[mi][ni], 0, 0, 0);
  }
}

// ------------------------------------- fused Q/K/V projection GEMM (N = 3072 virtual)
// Q, K -> plain [4096][1024] bf16 (coalesced); V -> [bh][dh][skv] packed ushort4.
__global__ __launch_bounds__(256, 3) void gemm_qkv(
    const u16* __restrict__ Xq, const u16* __restrict__ Xkv,
    const u16* __restrict__ WqT, const u16* __restrict__ WkvT,
    const float* __restrict__ bq, const float* __restrict__ bkv,
    u16* __restrict__ Qd, u16* __restrict__ Kd, u16* __restrict__ Vd) {
  __shared__ uint4 sA[512], sB[512];
  f32x4 acc[4][4] = {};
  const int n0 = blockIdx.x * 128, m0 = blockIdx.y * 128;
  const u16* A = (n0 < 1024) ? Xq : Xkv;
  const u16* Bt = (n0 < 1024) ? (WqT + (size_t)n0 * 1024)
                              : (WkvT + (size_t)(n0 - 1024) * 1024);
  const float* bias = (n0 < 1024) ? (bq + n0) : (bkv + (n0 - 1024));
  gemm_core<4>(A, Bt, m0, sA, sB, acc);

  const int tid = threadIdx.x, wv = tid >> 6, lane = tid & 63;
  const int quad = lane >> 4, l16 = lane & 15;
  const int wm = (wv >> 1) * 64, wn = (wv & 1) * 64;
  const int bb = m0 >> 11;
  const int gmb = m0 + wm + quad * 4;            // global row base (b*2048+ss)
  const int ssb = (m0 & 2047) + wm + quad * 4;   // seq base
#pragma unroll
  for (int ni = 0; ni < 4; ++ni) {
    const int gn = n0 + wn + ni * 16 + l16;      // virtual col; region uniform per ni
    const float bvn = bias[wn + ni * 16 + l16];
    if (gn < 1024) {                             // Q plain, pre-scaled
      u16* base = Qd + gn;
#pragma unroll
      for (int mi = 0; mi < 4; ++mi)
#pragma unroll
        for (int r = 0; r < 4; ++r)
          base[(size_t)(gmb + mi * 16 + r) * 1024] = f2bf((acc[mi][ni][r] + bvn) * QSCALE);
    } else if (gn < 2048) {                      // K plain
      u16* base = Kd + (gn - 1024);
#pragma unroll
      for (int mi = 0; mi < 4; ++mi)
#pragma unroll
        for (int r = 0; r < 4; ++r)
          base[(size_t)(gmb + mi * 16 + r) * 1024] = f2bf(acc[mi][ni][r] + bvn);
    } else {                                     // V^T: [bh][dh][skv], packed x4
      const int col = gn - 2048, hh = col >> 6, dh = col & 63;
      u16* base = Vd + ((size_t)(bb * 16 + hh) * 64 + dh) * 2048 + ssb;
#pragma unroll
      for (int mi = 0; mi < 4; ++mi) {
        ushort4 o;
        o.x = f2bf(acc[mi][ni][0] + bvn);
        o.y = f2bf(acc[mi][ni][1] + bvn);
        o.z = f2bf(acc[mi][ni][2] + bvn);
        o.w = f2bf(acc[mi][ni][3] + bvn);
        *(ushort4*)(base + mi * 16) = o;
      }
    }
  }
}

// ---------------------------------------------------------------- flash attention
// R6: LDS-traffic attack (R5 post-mortem: per-CU LDS pipe is the invariant wall).
// 256 thr = 4 waves, each wave owns 64 q-rows (BQ=256), grid 256 = 1 block/CU.
// 32x32x16 MFMA, swapped QK^T (S^T = K*Q: C col = q), so P converts to the PV
// A-fragment IN REGISTERS: 8 v_cvt_pk_bf16_f32 + 4 v_permlane32_swap_b32 per
// 32x32 S-tile. No sP LDS at all (-64KB/CU-iter); 64q/wave halves K/V frag
// re-reads (each wave reads the 8KB K tile once, regardless of q count).
// LDS traffic per CU-iter: 256KB -> 80KB (3.2x). lsum = 2 scalars/lane
// (S^T col = one q per lane), cross-half combined via permlane32_swap at end,
// transposed through a 1KB sL buffer for the row-indexed epilogue.
// exp2 via __builtin_amdgcn_exp2f (raw v_exp_f32, no libm expansion).
// Occupancy is 1 wave/SIMD by design: 32 independent MFMAs + 16 ds_reads per
// iter of within-wave ILP carry the pipes. XCD mapping: bid&31 = (h,b) slice,
// 8 q-blocks of the same slice land on one XCD's L2.
__global__ __launch_bounds__(256, 1) void flash_attn(
    const u16* __restrict__ Q, const u16* __restrict__ K,
    const u16* __restrict__ V, u16* __restrict__ O) {
  __shared__ uint4 sK[2][512];              // 64 kv x 64 dh, x2 buffers
  __shared__ uint4 sV[2][512];              // 64 dh x 64 kv (V^T), x2
  __shared__ float sL[256];                 // 1/lsum transpose, per-wave 64

  const int tid = threadIdx.x;
  const int wv = tid >> 6, lane = tid & 63;
  const int c = lane & 31, hh = lane >> 5;  // col-in-block, half
  const int hb = blockIdx.x & 31;           // fast dim: (h, b) -> fixes XCD
  const int q0 = (blockIdx.x >> 5) * 256;   // slow dim: q-block
  const int h = hb & 15, bz = hb >> 4;

  // Q,K plain [B*S][1024]; V^T [bh][dh][skv]
  const u16* Qb = Q + ((size_t)(bz * 2048 + q0 + wv * 64)) * 1024 + h * 64;
  const u16* Kb = K + ((size_t)(bz * 2048)) * 1024 + h * 64;
  const u16* Vb = V + ((size_t)(bz * 16 + h)) * 64 * 2048;

  // staging: slot i -> row i>>3, LDS chunk i&7 holds global chunk (i&7)^(row&7)
  const int i0 = wv * 128 + lane, i1 = i0 + 64;
  const int r0 = i0 >> 3, r1 = i1 >> 3;
  const int ck0 = (i0 & 7) ^ (r0 & 7), ck1 = (i1 & 7) ^ (r1 & 7);
  const u16* gK0 = Kb + (size_t)r0 * 1024 + ck0 * 8;
  const u16* gK1 = Kb + (size_t)r1 * 1024 + ck1 * 8;
  const u16* gV0 = Vb + (size_t)r0 * 2048 + ck0 * 8;
  const u16* gV1 = Vb + (size_t)r1 * 2048 + ck1 * 8;
  const int wo = wv * 128;

  // Q B-frags [g][s]: B[n=q][k=d], n = c, k = hh*8 + 16s + j
  bf16x8 qf[2][4];
#pragma unroll
  for (int g = 0; g < 2; ++g) {
    const u16* qr = Qb + (size_t)(32 * g + c) * 1024 + hh * 8;
#pragma unroll
    for (int s = 0; s < 4; ++s)
      qf[g][s] = as_bf16x8(*(const uint4*)(qr + 16 * s));
  }

  f32x16 oacc[2][2] = {};                   // [g][nb]: O[32g+qr][32nb+c]
  float lp[2] = {0.f, 0.f};                 // lsum partial per g (this half)

  // prologue: tile 0 -> buffer 0
  async16(gK0, &sK[0][wo]);
  async16(gK1, &sK[0][wo + 64]);
  async16(gV0, &sV[0][wo]);
  async16(gV1, &sV[0][wo + 64]);

  for (int t = 0; t < 32; ++t) {
    const int cur = t & 1;
    __syncthreads();   // drains loads for tile t (issued one iter ago)
    if (t < 31) {
      const size_t ko = (size_t)(t + 1) * 64 * 1024;   // 64 K rows (stride 1024)
      const int vo = (t + 1) * 64;                     // 64 kv cols
      async16(gK0 + ko, &sK[cur ^ 1][wo]);
      async16(gK1 + ko, &sK[cur ^ 1][wo + 64]);
      async16(gV0 + vo, &sV[cur ^ 1][wo]);
      async16(gV1 + vo, &sV[cur ^ 1][wo + 64]);
    }
    const uint4* K_ = sK[cur];
    const uint4* V_ = sV[cur];

    // K A-frags [b][s]: A[m=kv=32b+c][k=d], chunk (2s+hh)^(row&7)
    // V B-frags [nb][ks]: B[k=kv][n=dh=32nb+c], chunk (2ks+hh)^(row&7)
    bf16x8 kf[2][4], vf[2][4];
#pragma unroll
    for (int b = 0; b < 2; ++b) {
      const int row = 32 * b + c, sw = row & 7;
#pragma unroll
      for (int s = 0; s < 4; ++s) {
        kf[b][s] = as_bf16x8(K_[row * 8 + ((2 * s + hh) ^ sw)]);
        vf[b][s] = as_bf16x8(V_[row * 8 + ((2 * s + hh) ^ sw)]);
      }
    }

    // S^T per (b,g) -> exp2 -> in-register pack to PV A-frags pa[g][2b+sig]
    bf16x8 pa[2][4];
#pragma unroll
    for (int b = 0; b < 2; ++b)
#pragma unroll
      for (int g = 0; g < 2; ++g) {
        f32x16 sAcc = {};
#pragma unroll
        for (int s = 0; s < 4; ++s)
          sAcc = __builtin_amdgcn_mfma_f32_32x32x16_bf16(kf[b][s], qf[g][s], sAcc, 0, 0, 0);
        // lane holds S[q=c][kv32 = (r&3)+8*(r>>2)+4*hh] for this 32-kv block
        float e[16];
#pragma unroll
        for (int r = 0; r < 16; ++r) e[r] = __builtin_amdgcn_exp2f(sAcc[r]);
        float t0 = (e[0] + e[1]) + (e[2] + e[3]);
        float t1 = (e[4] + e[5]) + (e[6] + e[7]);
        float t2 = (e[8] + e[9]) + (e[10] + e[11]);
        float t3 = (e[12] + e[13]) + (e[14] + e[15]);
        lp[g] += (t0 + t1) + (t2 + t3);
        // pack pairs (kv even, odd) then cross-half swap: frag sig=0 covers
        // kv 0..15 of this block (k = 8*hh + j), sig=1 covers kv 16..31.
        u32 wA0 = pkbf(e[0], e[1]),   wA1 = pkbf(e[2], e[3]);
        u32 wB0 = pkbf(e[4], e[5]),   wB1 = pkbf(e[6], e[7]);
        u32 wC0 = pkbf(e[8], e[9]),   wC1 = pkbf(e[10], e[11]);
        u32 wD0 = pkbf(e[12], e[13]), wD1 = pkbf(e[14], e[15]);
        asm("v_permlane32_swap_b32 %0, %1" : "+v"(wA0), "+v"(wB0));
        asm("v_permlane32_swap_b32 %0, %1" : "+v"(wA1), "+v"(wB1));
        asm("v_permlane32_swap_b32 %0, %1" : "+v"(wC0), "+v"(wD0));
        asm("v_permlane32_swap_b32 %0, %1" : "+v"(wC1), "+v"(wD1));
        uint4 f0 = {wA0, wA1, wB0, wB1};
        uint4 f1 = {wC0, wC1, wD0, wD1};
        pa[g][2 * b]     = as_bf16x8(f0);
        pa[g][2 * b + 1] = as_bf16x8(f1);
      }

    // PV: O[q][dh] += P * V
#pragma unroll
    for (int g = 0; g < 2; ++g)
#pragma unroll
      for (int nb = 0; nb < 2; ++nb)
#pragma unroll
        for (int ks = 0; ks < 4; ++ks)
          oacc[g][nb] = __builtin_amdgcn_mfma_f32_32x32x16_bf16(
              pa[g][ks], vf[nb][ks], oacc[g][nb], 0, 0, 0);
  }

  // lsum: combine halves (each half summed its own kv rows), invert, transpose
#pragma unroll
  for (int g = 0; g < 2; ++g) {
    u32 a = __builtin_bit_cast(u32, lp[g]);
    u32 b = a;
    asm("v_permlane32_swap_b32 %0, %1" : "+v"(a), "+v"(b));
    float tot = __builtin_bit_cast(float, a) + __builtin_bit_cast(float, b);
    sL[wv * 64 + 32 * g + c] = 1.0f / tot;   // both halves write same value
  }

  // epilogue: O16 plain [4096][1024] bf16, normalized
#pragma unroll
  for (int g = 0; g < 2; ++g) {
    u16* Ob = O + ((size_t)(bz * 2048 + q0 + wv * 64 + 32 * g)) * 1024 + h * 64;
#pragma unroll
    for (int nb = 0; nb < 2; ++nb)
#pragma unroll
      for (int r = 0; r < 16; ++r) {
        const int qr = (r & 3) + 8 * (r >> 2) + 4 * hh;
        float rl = sL[wv * 64 + 32 * g + qr];   // broadcast read
        Ob[(size_t)qr * 1024 + nb * 32 + c] = f2bf(oacc[g][nb][r] * rl);
      }
  }
}

// ---------------------------------------------------------------- output projection
__global__ __launch_bounds__(256, 2) void gemm_out(
    const u16* __restrict__ A, const u16* __restrict__ Bt,
    const float* __restrict__ bias, float* __restrict__ C) {
  __shared__ uint4 sA[256], sB[512];
  f32x4 acc[2][4] = {};
  const int n0 = blockIdx.x * 128, m0 = blockIdx.y * 64;
  gemm_core<2>(A, Bt + (size_t)n0 * 1024, m0, sA, sB, acc);

  const int tid = threadIdx.x, wv = tid >> 6, lane = tid & 63;
  const int quad = lane >> 4, l16 = lane & 15;
  const int wm = (wv >> 1) * 32, wn = (wv & 1) * 64;
  float bv[4];
#pragma unroll
  for (int ni = 0; ni < 4; ++ni) bv[ni] = bias[n0 + wn + ni * 16 + l16];
#pragma unroll
  for (int mi = 0; mi < 2; ++mi)
#pragma unroll
    for (int ni = 0; ni < 4; ++ni)
#pragma unroll
      for (int r = 0; r < 4; ++r) {
        int gm = m0 + wm + mi * 16 + quad * 4 + r;
        int gn = n0 + wn + ni * 16 + l16;
        C[(size_t)gm * 1024 + gn] = acc[mi][ni][r] + bv[ni];
      }
}

extern "C" void kernel_launch(void* const* d_in, const int* in_sizes, int n_in,
                              void* d_out, int out_size, void* d_ws, size_t ws_size,
                              hipStream_t stream) {
  const float* xq  = (const float*)d_in[0];
  const float* xkv = (const float*)d_in[1];
  const float* Wq  = (const float*)d_in[2];
  const float* bq  = (const float*)d_in[3];
  const float* Wkv = (const float*)d_in[4];
  const float* bkv = (const float*)d_in[5];
  const float* Wo  = (const float*)d_in[6];
  const float* bo  = (const float*)d_in[7];
  float* out = (float*)d_out;

  char* p = (char*)d_ws;                       // 56 MiB total
  u16* Xq16  = (u16*)p; p += (size_t)8 << 20;  // [4096][1024] bf16
  u16* Xkv16 = (u16*)p; p += (size_t)8 << 20;
  u16* WqT   = (u16*)p; p += (size_t)2 << 20;  // [1024][1024]
  u16* WkvT  = (u16*)p; p += (size_t)4 << 20;  // [2048][1024]
  u16* WoT   = (u16*)p; p += (size_t)2 << 20;
  u16* Q16   = (u16*)p; p += (size_t)8 << 20;  // plain [4096][1024], pre-scaled
  u16* K16   = (u16*)p; p += (size_t)8 << 20;  // plain [4096][1024]
  u16* Vt16  = (u16*)p; p += (size_t)8 << 20;  // [bh][dh][skv]
  u16* O16   = (u16*)p; p += (size_t)8 << 20;  // plain [4096][1024]

  prep_kernel<<<14336, 256, 0, stream>>>(xq, xkv, Wq, Wkv, Wo,
                                         Xq16, Xkv16, WqT, WkvT, WoT);
  gemm_qkv<<<dim3(24, 32), 256, 0, stream>>>(Xq16, Xkv16, WqT, WkvT, bq, bkv,
                                             Q16, K16, Vt16);
  flash_attn<<<256, 256, 0, stream>>>(Q16, K16, Vt16, O16);
  gemm_out<<<dim3(8, 64), 256, 0, stream>>>(O16, WoT, bo, out);
}

// Round 4
// 195.377 us; speedup vs baseline: 1.0840x; 1.0787x over previous
//
#include <hip/hip_runtime.h>

typedef unsigned short u16;
typedef unsigned int u32;
typedef __bf16 bf16x8 __attribute__((ext_vector_type(8)));
typedef __bf16 bf16x2 __attribute__((ext_vector_type(2)));
typedef float f32x4 __attribute__((ext_vector_type(4)));
typedef float f32x16 __attribute__((ext_vector_type(16)));

#define QSCALE 0.18033688011112f  // 0.125 * log2(e): folded into Q so p = 2^s

__device__ __forceinline__ u16 f2bf(float f) {
  u32 u = __builtin_bit_cast(u32, f);
  u += 0x7fffu + ((u >> 16) & 1u);   // RNE
  return (u16)(u >> 16);
}

// packed f32x2 -> bf16x2 (RNE), emits v_cvt_pk_bf16_f32 on gfx950
__device__ __forceinline__ u32 pkbf(float a, float b) {
  bf16x2 t = {(__bf16)a, (__bf16)b};
  return __builtin_bit_cast(u32, t);
}

__device__ __forceinline__ bf16x8 as_bf16x8(uint4 v) {
  return __builtin_bit_cast(bf16x8, v);
}

// async global->LDS, 16B per lane; LDS dest = wave-uniform base + lane*16
__device__ __forceinline__ void async16(const void* g, void* l) {
  __builtin_amdgcn_global_load_lds(
      (__attribute__((address_space(1))) void*)(g),
      (__attribute__((address_space(3))) void*)(l), 16, 0, 0);
}

// ---------------- merged prep: cast xq/xkv to bf16 + transpose-cast 3 weights
__global__ void prep_kernel(const float* __restrict__ xq, const float* __restrict__ xkv,
                            const float* __restrict__ Wq, const float* __restrict__ Wkv,
                            const float* __restrict__ Wo,
                            u16* __restrict__ Xq16, u16* __restrict__ Xkv16,
                            u16* __restrict__ WqT, u16* __restrict__ WkvT,
                            u16* __restrict__ WoT) {
  const int bid = blockIdx.x, tid = threadIdx.x;
  if (bid < 8192) {
    int i = bid * 256 + tid;
    const float* s; u16* d; int j;
    if (i < 1048576) { s = xq; d = Xq16; j = i; }
    else             { s = xkv; d = Xkv16; j = i - 1048576; }
    float4 v = ((const float4*)s)[j];
    ushort4 o;
    o.x = f2bf(v.x); o.y = f2bf(v.y); o.z = f2bf(v.z); o.w = f2bf(v.w);
    ((ushort4*)d)[j] = o;
    return;
  }
  const int b2 = bid - 8192;
  const int z = b2 >> 11, rem = b2 & 2047;
  const int by = rem >> 6, bx = rem & 63;
  const float* src; u16* dst; int Nd;
  if (z == 0)      { src = Wq;  dst = WqT;  Nd = 1024; }
  else if (z == 1) { src = Wkv; dst = WkvT; Nd = 2048; }
  else             { src = Wo;  dst = WoT;  Nd = 1024; }
  const int n0 = bx * 32, k0 = by * 32;
  if (n0 >= Nd) return;
  __shared__ float tile[32][33];
  const int tx = tid & 31, ty = tid >> 5;  // 32 x 8
#pragma unroll
  for (int j = 0; j < 4; ++j)
    tile[ty + 8 * j][tx] = src[(size_t)(k0 + ty + 8 * j) * Nd + n0 + tx];
  __syncthreads();
#pragma unroll
  for (int j = 0; j < 4; ++j)
    dst[(size_t)(n0 + ty + 8 * j) * 1024 + k0 + tx] = f2bf(tile[tx][ty + 8 * j]);
}

// ---------------------------------------------------------------- GEMM core
template <int MI>
static __device__ __forceinline__ void gemm_core(
    const u16* __restrict__ A, const u16* __restrict__ Bt, int m0,
    uint4* sA, uint4* sB, f32x4 (*acc)[4]) {
  const int tid = threadIdx.x;
  const int wv = tid >> 6, lane = tid & 63;
  const int quad = lane >> 4, l16 = lane & 15;
  const int wm = (wv >> 1) * (MI * 16), wn = (wv & 1) * 64;

  const int ib0 = wv * 128 + lane, ib1 = ib0 + 64;      // B: 512 slots
  const int br0 = ib0 >> 2, bc0 = (ib0 & 3) ^ ((br0 >> 1) & 3);
  const int br1 = ib1 >> 2, bc1 = (ib1 & 3) ^ ((br1 >> 1) & 3);
  const u16* gB0 = Bt + (size_t)br0 * 1024 + bc0 * 8;
  const u16* gB1 = Bt + (size_t)br1 * 1024 + bc1 * 8;

  const int ia0 = wv * (MI * 32) + lane;                // A: MI*128 slots
  const int ar0 = ia0 >> 2, ac0 = (ia0 & 3) ^ ((ar0 >> 1) & 3);
  const u16* gA0 = A + (size_t)(m0 + ar0) * 1024 + ac0 * 8;
  const int ia1 = ia0 + 64;
  const int ar1 = ia1 >> 2, ac1 = (ia1 & 3) ^ ((ar1 >> 1) & 3);
  const u16* gA1 = A + (size_t)(m0 + ar1) * 1024 + ac1 * 8;
  uint4* sAw = sA + wv * (MI * 32);
  uint4* sBw = sB + wv * 128;

  for (int k0 = 0; k0 < 1024; k0 += 32) {
    __syncthreads();
    async16(gA0 + k0, sAw);
    if (MI == 4) async16(gA1 + k0, sAw + 64);
    async16(gB0 + k0, sBw);
    async16(gB1 + k0, sBw + 64);
    __syncthreads();

    bf16x8 af[MI], bfr[4];
#pragma unroll
    for (int mi = 0; mi < MI; ++mi) {
      int r = wm + mi * 16 + l16;
      af[mi] = as_bf16x8(sA[r * 4 + (quad ^ ((r >> 1) & 3))]);
    }
#pragma unroll
    for (int ni = 0; ni < 4; ++ni) {
      int r = wn + ni * 16 + l16;
      bfr[ni] = as_bf16x8(sB[r * 4 + (quad ^ ((r >> 1) & 3))]);
    }
#pragma unroll
    for (int mi = 0; mi < MI; ++mi)
#pragma unroll
      for (int ni = 0; ni < 4; ++ni)
        acc[mi][ni] = __builtin_amdgcn_mfma_f32_16x16x32_bf16(
            af[mi], bfr[ni], acc[mi][ni], 0, 0, 0);
  }
}

// ------------------------------------- fused Q/K/V projection GEMM (N = 3072 virtual)
// Q, K -> plain [4096][1024] bf16 (coalesced); V -> [bh][dh][skv] packed ushort4.
__global__ __launch_bounds__(256, 3) void gemm_qkv(
    const u16* __restrict__ Xq, const u16* __restrict__ Xkv,
    const u16* __restrict__ WqT, const u16* __restrict__ WkvT,
    const float* __restrict__ bq, const float* __restrict__ bkv,
    u16* __restrict__ Qd, u16* __restrict__ Kd, u16* __restrict__ Vd) {
  __shared__ uint4 sA[512], sB[512];
  f32x4 acc[4][4] = {};
  const int n0 = blockIdx.x * 128, m0 = blockIdx.y * 128;
  const u16* A = (n0 < 1024) ? Xq : Xkv;
  const u16* Bt = (n0 < 1024) ? (WqT + (size_t)n0 * 1024)
                              : (WkvT + (size_t)(n0 - 1024) * 1024);
  const float* bias = (n0 < 1024) ? (bq + n0) : (bkv + (n0 - 1024));
  gemm_core<4>(A, Bt, m0, sA, sB, acc);

  const int tid = threadIdx.x, wv = tid >> 6, lane = tid & 63;
  const int quad = lane >> 4, l16 = lane & 15;
  const int wm = (wv >> 1) * 64, wn = (wv & 1) * 64;
  const int bb = m0 >> 11;
  const int gmb = m0 + wm + quad * 4;            // global row base (b*2048+ss)
  const int ssb = (m0 & 2047) + wm + quad * 4;   // seq base
#pragma unroll
  for (int ni = 0; ni < 4; ++ni) {
    const int gn = n0 + wn + ni * 16 + l16;      // virtual col; region uniform per ni
    const float bvn = bias[wn + ni * 16 + l16];
    if (gn < 1024) {                             // Q plain, pre-scaled
      u16* base = Qd + gn;
#pragma unroll
      for (int mi = 0; mi < 4; ++mi)
#pragma unroll
        for (int r = 0; r < 4; ++r)
          base[(size_t)(gmb + mi * 16 + r) * 1024] = f2bf((acc[mi][ni][r] + bvn) * QSCALE);
    } else if (gn < 2048) {                      // K plain
      u16* base = Kd + (gn - 1024);
#pragma unroll
      for (int mi = 0; mi < 4; ++mi)
#pragma unroll
        for (int r = 0; r < 4; ++r)
          base[(size_t)(gmb + mi * 16 + r) * 1024] = f2bf(acc[mi][ni][r] + bvn);
    } else {                                     // V^T: [bh][dh][skv], packed x4
      const int col = gn - 2048, hh = col >> 6, dh = col & 63;
      u16* base = Vd + ((size_t)(bb * 16 + hh) * 64 + dh) * 2048 + ssb;
#pragma unroll
      for (int mi = 0; mi < 4; ++mi) {
        ushort4 o;
        o.x = f2bf(acc[mi][ni][0] + bvn);
        o.y = f2bf(acc[mi][ni][1] + bvn);
        o.z = f2bf(acc[mi][ni][2] + bvn);
        o.w = f2bf(acc[mi][ni][3] + bvn);
        *(ushort4*)(base + mi * 16) = o;
      }
    }
  }
}

// ---------------------------------------------------------------- flash attention
// R7 = R6 structure + kv-split wave groups (R6 post-mortem: 1 wave/SIMD left
// ~3.3k cyc/iter of dependency stall exposed; traffic was no longer the wall).
// 512 thr = 8 waves. Waves 0-3 (grp 0) process EVEN kv tiles, waves 4-7 (grp 1)
// ODD tiles; each group has its own K/V double-buffer. Per-wave structure is
// exactly R6 (64 q/wave, swapped 32x32 QK^T, in-register P, no sP LDS): per-CU
// LDS traffic per tile unchanged, but 2 waves/SIMD now cover each other's
// MFMA-chain/exp2/lgkm stalls. Half the barriers (16 tile-pair iters), and
// prefetch distance is effectively 2 tiles. Epilogue: grp 1 publishes partial
// O (f32, 64 KB LDS, used once) + lsum; grp 0 merges, normalizes, stores.
// LDS 133 KB -> 1 block/CU; launch_bounds(512,2) caps VGPR at 256 so the
// 8-wave block fits 2/SIMD. Grid unchanged: 256 = 32 hb x 8 q-blocks (XCD map).
__global__ __launch_bounds__(512, 2) void flash_attn(
    const u16* __restrict__ Q, const u16* __restrict__ K,
    const u16* __restrict__ V, u16* __restrict__ O) {
  __shared__ uint4 sK[2][2][512];           // [grp][dbuf]: 64 kv x 64 dh
  __shared__ uint4 sV[2][2][512];           // [grp][dbuf]: 64 dh x 64 kv (V^T)
  __shared__ float sO[16384];               // grp-1 partial O merge (64 KB)
  __shared__ float sLB[256];                // grp-1 lsum partials
  __shared__ float sLA[256];                // 1/ltot transpose (grp-0 private)

  const int tid = threadIdx.x;
  const int wv = tid >> 6, lane = tid & 63;
  const int grp = wv >> 2, wq = wv & 3;     // kv-parity group, q-subblock owner
  const int c = lane & 31, hh = lane >> 5;  // col-in-block, half
  const int hb = blockIdx.x & 31;           // fast dim: (h, b) -> fixes XCD
  const int q0 = (blockIdx.x >> 5) * 256;   // slow dim: q-block
  const int h = hb & 15, bz = hb >> 4;

  // Q,K plain [B*S][1024]; V^T [bh][dh][skv]. grp offset = 64 kv rows/cols.
  const u16* Qb = Q + ((size_t)(bz * 2048 + q0 + wq * 64)) * 1024 + h * 64;
  const u16* Kb = K + ((size_t)(bz * 2048 + grp * 64)) * 1024 + h * 64;
  const u16* Vb = V + ((size_t)(bz * 16 + h)) * 64 * 2048 + grp * 64;

  // staging: slot i -> row i>>3, LDS chunk i&7 holds global chunk (i&7)^(row&7)
  const int i0 = wq * 128 + lane, i1 = i0 + 64;
  const int r0 = i0 >> 3, r1 = i1 >> 3;
  const int ck0 = (i0 & 7) ^ (r0 & 7), ck1 = (i1 & 7) ^ (r1 & 7);
  const u16* gK0 = Kb + (size_t)r0 * 1024 + ck0 * 8;
  const u16* gK1 = Kb + (size_t)r1 * 1024 + ck1 * 8;
  const u16* gV0 = Vb + (size_t)r0 * 2048 + ck0 * 8;
  const u16* gV1 = Vb + (size_t)r1 * 2048 + ck1 * 8;
  const int wo = wq * 128;

  // Q B-frags [g][s]: B[n=q][k=d], n = c, k = hh*8 + 16s + j
  bf16x8 qf[2][4];
#pragma unroll
  for (int g = 0; g < 2; ++g) {
    const u16* qr = Qb + (size_t)(32 * g + c) * 1024 + hh * 8;
#pragma unroll
    for (int s = 0; s < 4; ++s)
      qf[g][s] = as_bf16x8(*(const uint4*)(qr + 16 * s));
  }

  f32x16 oacc[2][2] = {};                   // [g][nb]: O[32g+qr][32nb+c]
  float lp[2] = {0.f, 0.f};                 // lsum partial per g (this half)

  // prologue: this group's tile 0 (global tile = grp) -> buffer 0
  async16(gK0, &sK[grp][0][wo]);
  async16(gK1, &sK[grp][0][wo + 64]);
  async16(gV0, &sV[grp][0][wo]);
  async16(gV1, &sV[grp][0][wo + 64]);

  for (int t = 0; t < 16; ++t) {            // tile-pair loop; my tile = 2t+grp
    const int cur = t & 1;
    __syncthreads();   // drains my staging issued one iter ago
    if (t < 15) {
      const size_t ko = (size_t)(t + 1) * 128 * 1024;  // +2 tiles = 128 K rows
      const int vo = (t + 1) * 128;                    // 128 kv cols
      async16(gK0 + ko, &sK[grp][cur ^ 1][wo]);
      async16(gK1 + ko, &sK[grp][cur ^ 1][wo + 64]);
      async16(gV0 + vo, &sV[grp][cur ^ 1][wo]);
      async16(gV1 + vo, &sV[grp][cur ^ 1][wo + 64]);
    }
    const uint4* K_ = sK[grp][cur];
    const uint4* V_ = sV[grp][cur];

    // K A-frags [b][s]: A[m=kv=32b+c][k=d], chunk (2s+hh)^(row&7)
    // V B-frags [nb][ks]: B[k=kv][n=dh=32nb+c], chunk (2ks+hh)^(row&7)
    bf16x8 kf[2][4], vf[2][4];
#pragma unroll
    for (int b = 0; b < 2; ++b) {
      const int row = 32 * b + c, sw = row & 7;
#pragma unroll
      for (int s = 0; s < 4; ++s) {
        kf[b][s] = as_bf16x8(K_[row * 8 + ((2 * s + hh) ^ sw)]);
        vf[b][s] = as_bf16x8(V_[row * 8 + ((2 * s + hh) ^ sw)]);
      }
    }

    // S^T per (b,g) -> exp2 -> in-register pack to PV A-frags pa[g][2b+sig]
    bf16x8 pa[2][4];
#pragma unroll
    for (int b = 0; b < 2; ++b)
#pragma unroll
      for (int g = 0; g < 2; ++g) {
        f32x16 sAcc = {};
#pragma unroll
        for (int s = 0; s < 4; ++s)
          sAcc = __builtin_amdgcn_mfma_f32_32x32x16_bf16(kf[b][s], qf[g][s], sAcc, 0, 0, 0);
        // lane holds S[q=c][kv32 = (r&3)+8*(r>>2)+4*hh] for this 32-kv block
        float e[16];
#pragma unroll
        for (int r = 0; r < 16; ++r) e[r] = __builtin_amdgcn_exp2f(sAcc[r]);
        float t0 = (e[0] + e[1]) + (e[2] + e[3]);
        float t1 = (e[4] + e[5]) + (e[6] + e[7]);
        float t2 = (e[8] + e[9]) + (e[10] + e[11]);
        float t3 = (e[12] + e[13]) + (e[14] + e[15]);
        lp[g] += (t0 + t1) + (t2 + t3);
        // pack pairs (kv even, odd) then cross-half swap: frag sig=0 covers
        // kv 0..15 of this block (k = 8*hh + j), sig=1 covers kv 16..31.
        u32 wA0 = pkbf(e[0], e[1]),   wA1 = pkbf(e[2], e[3]);
        u32 wB0 = pkbf(e[4], e[5]),   wB1 = pkbf(e[6], e[7]);
        u32 wC0 = pkbf(e[8], e[9]),   wC1 = pkbf(e[10], e[11]);
        u32 wD0 = pkbf(e[12], e[13]), wD1 = pkbf(e[14], e[15]);
        asm("v_permlane32_swap_b32 %0, %1" : "+v"(wA0), "+v"(wB0));
        asm("v_permlane32_swap_b32 %0, %1" : "+v"(wA1), "+v"(wB1));
        asm("v_permlane32_swap_b32 %0, %1" : "+v"(wC0), "+v"(wD0));
        asm("v_permlane32_swap_b32 %0, %1" : "+v"(wC1), "+v"(wD1));
        uint4 f0 = {wA0, wA1, wB0, wB1};
        uint4 f1 = {wC0, wC1, wD0, wD1};
        pa[g][2 * b]     = as_bf16x8(f0);
        pa[g][2 * b + 1] = as_bf16x8(f1);
      }

    // PV: O[q][dh] += P * V
#pragma unroll
    for (int g = 0; g < 2; ++g)
#pragma unroll
      for (int nb = 0; nb < 2; ++nb)
#pragma unroll
        for (int ks = 0; ks < 4; ++ks)
          oacc[g][nb] = __builtin_amdgcn_mfma_f32_32x32x16_bf16(
              pa[g][ks], vf[nb][ks], oacc[g][nb], 0, 0, 0);
  }

  // lsum: combine the two 32-kv halves within this wave
  float rtot[2];
#pragma unroll
  for (int g = 0; g < 2; ++g) {
    u32 a = __builtin_bit_cast(u32, lp[g]);
    u32 b = a;
    asm("v_permlane32_swap_b32 %0, %1" : "+v"(a), "+v"(b));
    rtot[g] = __builtin_bit_cast(float, a) + __builtin_bit_cast(float, b);
  }

  if (grp) {
    // publish odd-tile partials: O to sO (lane-major, conflict-free), lsum to sLB
#pragma unroll
    for (int g = 0; g < 2; ++g) {
      sLB[wq * 64 + 32 * g + c] = rtot[g];   // both halves write same value
#pragma unroll
      for (int nb = 0; nb < 2; ++nb) {
        float* dst = sO + (wq * 4 + g * 2 + nb) * 1024;
#pragma unroll
        for (int r = 0; r < 16; ++r)
          dst[r * 64 + lane] = oacc[g][nb][r];
      }
    }
  }
  __syncthreads();
  if (!grp) {
    // merge, invert lsum (sLA wave-private: lgkm ordering suffices), store O
#pragma unroll
    for (int g = 0; g < 2; ++g) {
#pragma unroll
      for (int nb = 0; nb < 2; ++nb) {
        const float* srcp = sO + (wq * 4 + g * 2 + nb) * 1024;
#pragma unroll
        for (int r = 0; r < 16; ++r)
          oacc[g][nb][r] += srcp[r * 64 + lane];
      }
      float tot = rtot[g] + sLB[wq * 64 + 32 * g + c];
      sLA[wq * 64 + 32 * g + c] = 1.0f / tot;
    }
#pragma unroll
    for (int g = 0; g < 2; ++g) {
      u16* Ob = O + ((size_t)(bz * 2048 + q0 + wq * 64 + 32 * g)) * 1024 + h * 64;
#pragma unroll
      for (int nb = 0; nb < 2; ++nb)
#pragma unroll
        for (int r = 0; r < 16; ++r) {
          const int qr = (r & 3) + 8 * (r >> 2) + 4 * hh;
          float rl = sLA[wq * 64 + 32 * g + qr];   // broadcast read
          Ob[(size_t)qr * 1024 + nb * 32 + c] = f2bf(oacc[g][nb][r] * rl);
        }
    }
  }
}

// ---------------------------------------------------------------- output projection
__global__ __launch_bounds__(256, 2) void gemm_out(
    const u16* __restrict__ A, const u16* __restrict__ Bt,
    const float* __restrict__ bias, float* __restrict__ C) {
  __shared__ uint4 sA[256], sB[512];
  f32x4 acc[2][4] = {};
  const int n0 = blockIdx.x * 128, m0 = blockIdx.y * 64;
  gemm_core<2>(A, Bt + (size_t)n0 * 1024, m0, sA, sB, acc);

  const int tid = threadIdx.x, wv = tid >> 6, lane = tid & 63;
  const int quad = lane >> 4, l16 = lane & 15;
  const int wm = (wv >> 1) * 32, wn = (wv & 1) * 64;
  float bv[4];
#pragma unroll
  for (int ni = 0; ni < 4; ++ni) bv[ni] = bias[n0 + wn + ni * 16 + l16];
#pragma unroll
  for (int mi = 0; mi < 2; ++mi)
#pragma unroll
    for (int ni = 0; ni < 4; ++ni)
#pragma unroll
      for (int r = 0; r < 4; ++r) {
        int gm = m0 + wm + mi * 16 + quad * 4 + r;
        int gn = n0 + wn + ni * 16 + l16;
        C[(size_t)gm * 1024 + gn] = acc[mi][ni][r] + bv[ni];
      }
}

extern "C" void kernel_launch(void* const* d_in, const int* in_sizes, int n_in,
                              void* d_out, int out_size, void* d_ws, size_t ws_size,
                              hipStream_t stream) {
  const float* xq  = (const float*)d_in[0];
  const float* xkv = (const float*)d_in[1];
  const float* Wq  = (const float*)d_in[2];
  const float* bq  = (const float*)d_in[3];
  const float* Wkv = (const float*)d_in[4];
  const float* bkv = (const float*)d_in[5];
  const float* Wo  = (const float*)d_in[6];
  const float* bo  = (const float*)d_in[7];
  float* out = (float*)d_out;

  char* p = (char*)d_ws;                       // 56 MiB total
  u16* Xq16  = (u16*)p; p += (size_t)8 << 20;  // [4096][1024] bf16
  u16* Xkv16 = (u16*)p; p += (size_t)8 << 20;
  u16* WqT   = (u16*)p; p += (size_t)2 << 20;  // [1024][1024]
  u16* WkvT  = (u16*)p; p += (size_t)4 << 20;  // [2048][1024]
  u16* WoT   = (u16*)p; p += (size_t)2 << 20;
  u16* Q16   = (u16*)p; p += (size_t)8 << 20;  // plain [4096][1024], pre-scaled
  u16* K16   = (u16*)p; p += (size_t)8 << 20;  // plain [4096][1024]
  u16* Vt16  = (u16*)p; p += (size_t)8 << 20;  // [bh][dh][skv]
  u16* O16   = (u16*)p; p += (size_t)8 << 20;  // plain [4096][1024]

  prep_kernel<<<14336, 256, 0, stream>>>(xq, xkv, Wq, Wkv, Wo,
                                         Xq16, Xkv16, WqT, WkvT, WoT);
  gemm_qkv<<<dim3(24, 32), 256, 0, stream>>>(Xq16, Xkv16, WqT, WkvT, bq, bkv,
                                             Q16, K16, Vt16);
  flash_attn<<<256, 512, 0, stream>>>(Q16, K16, Vt16, O16);
  gemm_out<<<dim3(8, 64), 256, 0, stream>>>(O16, WoT, bo, out);
}